// Round 1
// baseline (1502.179 us; speedup 1.0000x reference)
//
#include <hip/hip_runtime.h>
#include <hip/hip_bf16.h>
#include <math.h>

#define B_ 8
#define N_ 8192
#define D_ 512
#define G_ 64
#define M_ (B_ * N_)  // 65536

// ---------------- kernel 0: deterministic group member lists ----------------
__global__ __launch_bounds__(256) void build_lists(const int* __restrict__ ids,
                                                   int* __restrict__ counts,
                                                   int* __restrict__ base,
                                                   int* __restrict__ list) {
    __shared__ int s_ids[N_];      // 32 KB
    __shared__ int s_cnt[G_];
    __shared__ int s_base[G_];
    for (int i = threadIdx.x; i < N_; i += blockDim.x) s_ids[i] = ids[i];
    __syncthreads();
    int tid = threadIdx.x;
    if (tid < G_) {
        int c = 0;
#pragma unroll 8
        for (int n = 0; n < N_; ++n) c += (s_ids[n] == tid) ? 1 : 0;
        s_cnt[tid] = c;
    }
    __syncthreads();
    if (tid == 0) {
        int acc = 0;
        for (int g = 0; g < G_; ++g) { s_base[g] = acc; acc += s_cnt[g]; }
    }
    __syncthreads();
    if (tid < G_) {
        int w = s_base[tid];
        for (int n = 0; n < N_; ++n)
            if (s_ids[n] == tid) list[w++] = n;
        counts[tid] = s_cnt[tid];
        base[tid]   = s_base[tid];
    }
}

// ---------------- kernel 1: fused dual GEMM a = xW1^T+b1, v = xW2^T+b2 ------
#define BM 64
#define BN 64
#define BK 16

__global__ __launch_bounds__(256) void gemm12(const float* __restrict__ x,
                                              const float* __restrict__ w1,
                                              const float* __restrict__ b1,
                                              const float* __restrict__ w2,
                                              const float* __restrict__ b2,
                                              float* __restrict__ a_out,
                                              float* __restrict__ v_out) {
    __shared__ float xs[BK][BM + 4];
    __shared__ float w1s[BK][BN + 4];
    __shared__ float w2s[BK][BN + 4];
    const int m0 = blockIdx.x * BM;
    const int n0 = blockIdx.y * BN;
    const int tid = threadIdx.x;
    const int tr = tid >> 4;        // 0..15
    const int tc = tid & 15;        // 0..15
    const int lrow = tid >> 2;      // 0..63
    const int lk4 = (tid & 3) * 4;  // 0,4,8,12

    float acc_a[4][4] = {};
    float acc_v[4][4] = {};

    for (int k0 = 0; k0 < D_; k0 += BK) {
        float4 xv  = *(const float4*)(x  + (size_t)(m0 + lrow) * D_ + k0 + lk4);
        float4 w1v = *(const float4*)(w1 + (size_t)(n0 + lrow) * D_ + k0 + lk4);
        float4 w2v = *(const float4*)(w2 + (size_t)(n0 + lrow) * D_ + k0 + lk4);
        __syncthreads();
        xs[lk4 + 0][lrow] = xv.x;  xs[lk4 + 1][lrow] = xv.y;
        xs[lk4 + 2][lrow] = xv.z;  xs[lk4 + 3][lrow] = xv.w;
        w1s[lk4 + 0][lrow] = w1v.x; w1s[lk4 + 1][lrow] = w1v.y;
        w1s[lk4 + 2][lrow] = w1v.z; w1s[lk4 + 3][lrow] = w1v.w;
        w2s[lk4 + 0][lrow] = w2v.x; w2s[lk4 + 1][lrow] = w2v.y;
        w2s[lk4 + 2][lrow] = w2v.z; w2s[lk4 + 3][lrow] = w2v.w;
        __syncthreads();
#pragma unroll
        for (int kk = 0; kk < BK; ++kk) {
            float4 x4 = *(const float4*)&xs[kk][tr * 4];
            float4 p4 = *(const float4*)&w1s[kk][tc * 4];
            float4 q4 = *(const float4*)&w2s[kk][tc * 4];
            float xa[4] = {x4.x, x4.y, x4.z, x4.w};
            float pa[4] = {p4.x, p4.y, p4.z, p4.w};
            float qa[4] = {q4.x, q4.y, q4.z, q4.w};
#pragma unroll
            for (int i = 0; i < 4; ++i)
#pragma unroll
                for (int j = 0; j < 4; ++j) {
                    acc_a[i][j] = fmaf(xa[i], pa[j], acc_a[i][j]);
                    acc_v[i][j] = fmaf(xa[i], qa[j], acc_v[i][j]);
                }
        }
    }

    float bb1[4], bb2[4];
#pragma unroll
    for (int j = 0; j < 4; ++j) {
        bb1[j] = b1[n0 + tc * 4 + j];
        bb2[j] = b2[n0 + tc * 4 + j];
    }
#pragma unroll
    for (int i = 0; i < 4; ++i) {
        size_t o = (size_t)(m0 + tr * 4 + i) * D_ + n0 + tc * 4;
        float4 ra, rv;
        ra.x = acc_a[i][0] + bb1[0]; ra.y = acc_a[i][1] + bb1[1];
        ra.z = acc_a[i][2] + bb1[2]; ra.w = acc_a[i][3] + bb1[3];
        rv.x = acc_v[i][0] + bb2[0]; rv.y = acc_v[i][1] + bb2[1];
        rv.z = acc_v[i][2] + bb2[2]; rv.w = acc_v[i][3] + bb2[3];
        *(float4*)(a_out + o) = ra;
        *(float4*)(v_out + o) = rv;
    }
}

// ---------------- kernel 2: online segment softmax + weighted value sum -----
__global__ __launch_bounds__(256) void softagg(const float* __restrict__ a,
                                               const float* __restrict__ v,
                                               const int* __restrict__ counts,
                                               const int* __restrict__ base,
                                               const int* __restrict__ list,
                                               float* __restrict__ y) {
    const int g = blockIdx.x;
    const int b = blockIdx.y;
    const int e = threadIdx.x * 2;
    const int cnt = counts[g];
    const int bs = base[g];

    float m0 = -INFINITY, m1 = -INFINITY;
    float d0 = 0.f, d1 = 0.f, y0 = 0.f, y1 = 0.f;

    for (int i = 0; i < cnt; ++i) {
        int n = list[bs + i];
        size_t off = ((size_t)b * N_ + n) * D_ + e;
        float2 av = *(const float2*)(a + off);
        float2 vv = *(const float2*)(v + off);

        float nm0 = fmaxf(m0, av.x);
        float c0 = __expf(m0 - nm0);
        float p0 = __expf(av.x - nm0);
        d0 = d0 * c0 + p0;
        y0 = y0 * c0 + p0 * vv.x;
        m0 = nm0;

        float nm1 = fmaxf(m1, av.y);
        float c1 = __expf(m1 - nm1);
        float p1 = __expf(av.y - nm1);
        d1 = d1 * c1 + p1;
        y1 = y1 * c1 + p1 * vv.y;
        m1 = nm1;
    }
    size_t yoff = ((size_t)b * G_ + g) * D_ + e;
    y[yoff]     = y0 / d0;
    y[yoff + 1] = y1 / d1;
}

// ---------------- kernel 3: out_small = y W3^T + b3 -------------------------
__global__ __launch_bounds__(256) void gemm3(const float* __restrict__ y,
                                             const float* __restrict__ w3,
                                             const float* __restrict__ b3,
                                             float* __restrict__ out_small) {
    __shared__ float ys[BK][BM + 4];
    __shared__ float wss[BK][BN + 4];
    const int m0 = blockIdx.x * BM;
    const int n0 = blockIdx.y * BN;
    const int tid = threadIdx.x;
    const int tr = tid >> 4;
    const int tc = tid & 15;
    const int lrow = tid >> 2;
    const int lk4 = (tid & 3) * 4;

    float acc[4][4] = {};

    for (int k0 = 0; k0 < D_; k0 += BK) {
        float4 yv = *(const float4*)(y  + (size_t)(m0 + lrow) * D_ + k0 + lk4);
        float4 wv = *(const float4*)(w3 + (size_t)(n0 + lrow) * D_ + k0 + lk4);
        __syncthreads();
        ys[lk4 + 0][lrow] = yv.x;  ys[lk4 + 1][lrow] = yv.y;
        ys[lk4 + 2][lrow] = yv.z;  ys[lk4 + 3][lrow] = yv.w;
        wss[lk4 + 0][lrow] = wv.x; wss[lk4 + 1][lrow] = wv.y;
        wss[lk4 + 2][lrow] = wv.z; wss[lk4 + 3][lrow] = wv.w;
        __syncthreads();
#pragma unroll
        for (int kk = 0; kk < BK; ++kk) {
            float4 y4 = *(const float4*)&ys[kk][tr * 4];
            float4 w4 = *(const float4*)&wss[kk][tc * 4];
            float ya[4] = {y4.x, y4.y, y4.z, y4.w};
            float wa[4] = {w4.x, w4.y, w4.z, w4.w};
#pragma unroll
            for (int i = 0; i < 4; ++i)
#pragma unroll
                for (int j = 0; j < 4; ++j)
                    acc[i][j] = fmaf(ya[i], wa[j], acc[i][j]);
        }
    }

    float bb[4];
#pragma unroll
    for (int j = 0; j < 4; ++j) bb[j] = b3[n0 + tc * 4 + j];
#pragma unroll
    for (int i = 0; i < 4; ++i) {
        size_t o = (size_t)(m0 + tr * 4 + i) * D_ + n0 + tc * 4;
        float4 r;
        r.x = acc[i][0] + bb[0]; r.y = acc[i][1] + bb[1];
        r.z = acc[i][2] + bb[2]; r.w = acc[i][3] + bb[3];
        *(float4*)(out_small + o) = r;
    }
}

// ---------------- kernel 4: gather group outputs back to rows ---------------
__global__ __launch_bounds__(256) void gather_out(const int* __restrict__ ids,
                                                  const float* __restrict__ out_small,
                                                  float* __restrict__ out) {
    const int c = blockIdx.x * 256 + threadIdx.x;   // one float4 chunk
    const int per_row = D_ / 4;                     // 128
    const int b = c / (N_ * per_row);
    const int rem = c % (N_ * per_row);
    const int n = rem / per_row;
    const int q = rem % per_row;
    const int g = ids[n];
    float4 val = *(const float4*)(out_small + ((size_t)b * G_ + g) * D_ + q * 4);
    *(float4*)(out + (size_t)c * 4) = val;
}

// ---------------- launcher --------------------------------------------------
extern "C" void kernel_launch(void* const* d_in, const int* in_sizes, int n_in,
                              void* d_out, int out_size, void* d_ws, size_t ws_size,
                              hipStream_t stream) {
    (void)in_sizes; (void)n_in; (void)out_size; (void)ws_size;
    const float* x  = (const float*)d_in[0];
    const int*   ids = (const int*)d_in[1];
    const float* w1 = (const float*)d_in[2];
    const float* b1 = (const float*)d_in[3];
    const float* w2 = (const float*)d_in[4];
    const float* b2 = (const float*)d_in[5];
    const float* w3 = (const float*)d_in[6];
    const float* b3 = (const float*)d_in[7];
    float* out = (float*)d_out;

    float* ws_f      = (float*)d_ws;
    float* y         = ws_f;                    // [B,G,D]  1 MB
    float* out_small = ws_f + 262144;           // [B*G,D]  1 MB
    int*   counts    = (int*)(ws_f + 524288);   // 64
    int*   base      = counts + 64;             // 64
    int*   list      = base + 64;               // 8192
    float* v         = ws_f + 524288 + 8320;    // [M,D] 128 MB (16B aligned)
    float* a         = out;                     // reuse d_out as scratch for a

    hipLaunchKernelGGL(build_lists, dim3(1), dim3(256), 0, stream, ids, counts, base, list);
    hipLaunchKernelGGL(gemm12, dim3(M_ / BM, D_ / BN), dim3(256), 0, stream,
                       x, w1, b1, w2, b2, a, v);
    hipLaunchKernelGGL(softagg, dim3(G_, B_), dim3(256), 0, stream,
                       a, v, counts, base, list, y);
    hipLaunchKernelGGL(gemm3, dim3(512 / BM, 512 / BN), dim3(256), 0, stream,
                       y, w3, b3, out_small);
    hipLaunchKernelGGL(gather_out, dim3((int)((size_t)B_ * N_ * D_ / 4 / 256)), dim3(256), 0, stream,
                       ids, out_small, out);
}

// Round 2
// 249.541 us; speedup vs baseline: 6.0198x; 6.0198x over previous
//
#include <hip/hip_runtime.h>
#include <hip/hip_bf16.h>
#include <math.h>

#define B_ 8
#define N_ 8192
#define D_ 512
#define G_ 64
#define M_ (B_ * N_)   // 65536
#define NF 1024        // fused output dim: cols 0..511 = a, 512..1023 = v
#define SPLIT 8
#define LSTRIDE 256    // per-group list stride (cnt ~ Binom(8192,1/64) ~ 128, 256 is safe)

typedef short bf16x8 __attribute__((ext_vector_type(8)));
typedef float f32x4 __attribute__((ext_vector_type(4)));
typedef unsigned short ushortT;

__device__ __forceinline__ unsigned short f2bf(float f) {
    __hip_bfloat16 h = __float2bfloat16(f);
    return *reinterpret_cast<unsigned short*>(&h);
}
__device__ __forceinline__ float bf2f(unsigned int bits16) {
    return __uint_as_float(bits16 << 16);
}
__device__ __forceinline__ void gload_lds16(const void* g, void* l) {
    __builtin_amdgcn_global_load_lds((const __attribute__((address_space(1))) void*)g,
                                     (__attribute__((address_space(3))) void*)l,
                                     16, 0, 0);
}

// ---------------- cast kernels ---------------------------------------------
__global__ __launch_bounds__(256) void cast_x(const float* __restrict__ x,
                                              unsigned short* __restrict__ xb) {
    size_t t = (size_t)blockIdx.x * 256 + threadIdx.x;   // one float4
    float4 f = *(const float4*)(x + t * 4);
    ushort4 u;
    u.x = f2bf(f.x); u.y = f2bf(f.y); u.z = f2bf(f.z); u.w = f2bf(f.w);
    *(ushort4*)(xb + t * 4) = u;
}

__global__ __launch_bounds__(256) void cast_w(const float* __restrict__ w1,
                                              const float* __restrict__ b1,
                                              const float* __restrict__ w2,
                                              const float* __restrict__ b2,
                                              unsigned short* __restrict__ wB,
                                              float* __restrict__ biasB) {
    int t = blockIdx.x * 256 + threadIdx.x;   // 0..131071, one float4
    int idx = t * 4;
    int row = idx >> 9;
    int col = idx & 511;
    const float* src = (row < 512) ? (w1 + (size_t)row * 512 + col)
                                   : (w2 + (size_t)(row - 512) * 512 + col);
    float4 f = *(const float4*)src;
    ushort4 u;
    u.x = f2bf(f.x); u.y = f2bf(f.y); u.z = f2bf(f.z); u.w = f2bf(f.w);
    *(ushort4*)(wB + idx) = u;
    if (t < 1024) biasB[t] = (t < 512) ? b1[t] : b2[t - 512];
}

// ---------------- group member lists (one block per group) ------------------
__global__ __launch_bounds__(256) void build_lists2(const int* __restrict__ ids,
                                                    int* __restrict__ counts,
                                                    int* __restrict__ list) {
    __shared__ int sid[N_];     // 32 KB
    __shared__ int scnt[256];
    const int g = blockIdx.x;
    const int t = threadIdx.x;
    for (int i = t; i < N_; i += 256) sid[i] = ids[i];
    __syncthreads();
    int c = 0;
    const int nb = t * 32;
#pragma unroll 8
    for (int k = 0; k < 32; ++k) c += (sid[nb + k] == g) ? 1 : 0;
    scnt[t] = c;
    __syncthreads();
    if (t == 0) {
        int run = 0;
        for (int i = 0; i < 256; ++i) { int x = scnt[i]; scnt[i] = run; run += x; }
        counts[g] = run;
    }
    __syncthreads();
    int pos = g * LSTRIDE + scnt[t];
    for (int k = 0; k < 32; ++k)
        if (sid[nb + k] == g) list[pos++] = nb + k;
}

// ---------------- fused MFMA GEMM: av = [x @ w1^T+b1 || x @ w2^T+b2] (bf16) -
// M=65536, N=1024, K=512.  128x128 tile, BK=64, 4 waves (2x2), 16x16x32 MFMA.
__global__ __launch_bounds__(256) void gemm12_mfma(const unsigned short* __restrict__ xb,
                                                   const unsigned short* __restrict__ wB,
                                                   const float* __restrict__ biasB,
                                                   unsigned short* __restrict__ av) {
    __shared__ unsigned short lsA[128 * 64];   // 16 KB, linear [row][k]
    __shared__ unsigned short lsB[128 * 64];   // 16 KB
    const int m0 = blockIdx.x * 128;
    const int n0 = blockIdx.y * 128;
    const int tid = threadIdx.x;
    const int l = tid & 63;
    const int w = tid >> 6;            // wave 0..3
    const int wm = w >> 1, wn = w & 1; // 2x2 wave grid, 64x64 per wave

    // staging geometry: chunk = 1KB = 8 rows x 64 cols(bf16); wave stages 4 chunks/tile
    const int lr = l >> 3;            // row within chunk 0..7
    const int lc = (l & 7) * 8;       // elem col within row

    // fragment geometry
    const int fr = l & 15;
    const int ko = (l >> 4) * 8;
    const int r4 = (l >> 4) * 4;

    f32x4 acc[4][4];
#pragma unroll
    for (int i = 0; i < 4; ++i)
#pragma unroll
        for (int j = 0; j < 4; ++j) acc[i][j] = (f32x4){0.f, 0.f, 0.f, 0.f};

    for (int kt = 0; kt < 512; kt += 64) {
        // ---- stage A and B tiles (global_load_lds width=16) ----
#pragma unroll
        for (int q = 0; q < 4; ++q) {
            const int c = w * 4 + q;                 // chunk 0..15
            const int row = c * 8 + lr;
            gload_lds16(xb + (size_t)(m0 + row) * 512 + kt + lc, &lsA[c * 512]);
            gload_lds16(wB + (size_t)(n0 + row) * 512 + kt + lc, &lsB[c * 512]);
        }
        __syncthreads();   // drains vmcnt -> LDS valid
        // ---- compute: 2 k-subs of 32 ----
#pragma unroll
        for (int ks = 0; ks < 2; ++ks) {
            bf16x8 af[4], bf[4];
#pragma unroll
            for (int i = 0; i < 4; ++i)
                af[i] = *(const bf16x8*)&lsA[(wm * 64 + i * 16 + fr) * 64 + ks * 32 + ko];
#pragma unroll
            for (int j = 0; j < 4; ++j)
                bf[j] = *(const bf16x8*)&lsB[(wn * 64 + j * 16 + fr) * 64 + ks * 32 + ko];
#pragma unroll
            for (int i = 0; i < 4; ++i)
#pragma unroll
                for (int j = 0; j < 4; ++j)
                    acc[i][j] = __builtin_amdgcn_mfma_f32_16x16x32_bf16(af[i], bf[j], acc[i][j], 0, 0, 0);
        }
        __syncthreads();   // everyone done reading before next stage overwrites
    }

    // ---- epilogue: bias + bf16 store ----
#pragma unroll
    for (int j = 0; j < 4; ++j) {
        const int col = n0 + wn * 64 + j * 16 + fr;
        const float bj = biasB[col];
#pragma unroll
        for (int i = 0; i < 4; ++i) {
            const int mrow = m0 + wm * 64 + i * 16 + r4;
#pragma unroll
            for (int r = 0; r < 4; ++r)
                av[(size_t)(mrow + r) * NF + col] = f2bf(acc[i][j][r] + bj);
        }
    }
}

// ---------------- segment softmax (no max; exp-sum), split over rows --------
__global__ __launch_bounds__(256) void softaggA(const unsigned short* __restrict__ av,
                                                const int* __restrict__ counts,
                                                const int* __restrict__ list,
                                                float* __restrict__ pd,
                                                float* __restrict__ py) {
    const int g = blockIdx.x, b = blockIdx.y, s = blockIdx.z;
    const int e0 = threadIdx.x * 2;
    const int cnt = counts[g];
    float d0 = 0.f, d1 = 0.f, y0 = 0.f, y1 = 0.f;
    for (int i = s; i < cnt; i += SPLIT) {
        const int n = list[g * LSTRIDE + i];
        const unsigned short* row = av + (size_t)(b * N_ + n) * NF;
        const unsigned pa = *(const unsigned*)(row + e0);
        const unsigned pv = *(const unsigned*)(row + 512 + e0);
        const float a0 = bf2f(pa & 0xFFFFu);
        const float a1 = __uint_as_float(pa & 0xFFFF0000u);
        const float v0 = bf2f(pv & 0xFFFFu);
        const float v1 = __uint_as_float(pv & 0xFFFF0000u);
        const float ea0 = __expf(a0), ea1 = __expf(a1);
        d0 += ea0; d1 += ea1;
        y0 = fmaf(ea0, v0, y0); y1 = fmaf(ea1, v1, y1);
    }
    const size_t o = (((size_t)s * G_ + g) * B_ + b) * D_ + e0;
    pd[o] = d0; pd[o + 1] = d1;
    py[o] = y0; py[o + 1] = y1;
}

__global__ __launch_bounds__(256) void combineB(const float* __restrict__ pd,
                                                const float* __restrict__ py,
                                                float* __restrict__ y) {
    const int g = blockIdx.x, b = blockIdx.y;
    const int e0 = threadIdx.x * 2;
    float d0 = 0.f, d1 = 0.f, s0 = 0.f, s1 = 0.f;
#pragma unroll
    for (int s = 0; s < SPLIT; ++s) {
        const size_t o = (((size_t)s * G_ + g) * B_ + b) * D_ + e0;
        d0 += pd[o]; d1 += pd[o + 1];
        s0 += py[o]; s1 += py[o + 1];
    }
    const size_t yo = ((size_t)b * G_ + g) * D_ + e0;
    y[yo] = s0 / d0;
    y[yo + 1] = s1 / d1;
}

// ---------------- small GEMM: out_small = y @ w3^T + b3 (f32 vector) --------
__global__ __launch_bounds__(256) void gemm3(const float* __restrict__ y,
                                             const float* __restrict__ w3,
                                             const float* __restrict__ b3,
                                             float* __restrict__ out_small) {
    __shared__ float ys[16][68];
    __shared__ float wss[16][68];
    const int m0 = blockIdx.x * 64;
    const int n0 = blockIdx.y * 64;
    const int tid = threadIdx.x;
    const int tr = tid >> 4;
    const int tc = tid & 15;
    const int lrow = tid >> 2;
    const int lk4 = (tid & 3) * 4;

    float acc[4][4] = {};

    for (int k0 = 0; k0 < D_; k0 += 16) {
        float4 yv = *(const float4*)(y + (size_t)(m0 + lrow) * D_ + k0 + lk4);
        float4 wv = *(const float4*)(w3 + (size_t)(n0 + lrow) * D_ + k0 + lk4);
        __syncthreads();
        ys[lk4 + 0][lrow] = yv.x;  ys[lk4 + 1][lrow] = yv.y;
        ys[lk4 + 2][lrow] = yv.z;  ys[lk4 + 3][lrow] = yv.w;
        wss[lk4 + 0][lrow] = wv.x; wss[lk4 + 1][lrow] = wv.y;
        wss[lk4 + 2][lrow] = wv.z; wss[lk4 + 3][lrow] = wv.w;
        __syncthreads();
#pragma unroll
        for (int kk = 0; kk < 16; ++kk) {
            float4 y4 = *(const float4*)&ys[kk][tr * 4];
            float4 w4 = *(const float4*)&wss[kk][tc * 4];
            float ya[4] = {y4.x, y4.y, y4.z, y4.w};
            float wa[4] = {w4.x, w4.y, w4.z, w4.w};
#pragma unroll
            for (int i = 0; i < 4; ++i)
#pragma unroll
                for (int j = 0; j < 4; ++j)
                    acc[i][j] = fmaf(ya[i], wa[j], acc[i][j]);
        }
    }

    float bb[4];
#pragma unroll
    for (int j = 0; j < 4; ++j) bb[j] = b3[n0 + tc * 4 + j];
#pragma unroll
    for (int i = 0; i < 4; ++i) {
        size_t o = (size_t)(m0 + tr * 4 + i) * D_ + n0 + tc * 4;
        float4 r;
        r.x = acc[i][0] + bb[0]; r.y = acc[i][1] + bb[1];
        r.z = acc[i][2] + bb[2]; r.w = acc[i][3] + bb[3];
        *(float4*)(out_small + o) = r;
    }
}

// ---------------- gather group outputs back to rows -------------------------
__global__ __launch_bounds__(256) void gather_out(const int* __restrict__ ids,
                                                  const float* __restrict__ out_small,
                                                  float* __restrict__ out) {
    const int c = blockIdx.x * 256 + threadIdx.x;   // one float4 chunk
    const int per_row = D_ / 4;                     // 128
    const int b = c / (N_ * per_row);
    const int rem = c % (N_ * per_row);
    const int n = rem / per_row;
    const int q = rem % per_row;
    const int g = ids[n];
    float4 val = *(const float4*)(out_small + ((size_t)b * G_ + g) * D_ + q * 4);
    *(float4*)(out + (size_t)c * 4) = val;
}

// ---------------- launcher --------------------------------------------------
extern "C" void kernel_launch(void* const* d_in, const int* in_sizes, int n_in,
                              void* d_out, int out_size, void* d_ws, size_t ws_size,
                              hipStream_t stream) {
    (void)in_sizes; (void)n_in; (void)out_size; (void)ws_size;
    const float* x   = (const float*)d_in[0];
    const int*   ids = (const int*)d_in[1];
    const float* w1  = (const float*)d_in[2];
    const float* b1  = (const float*)d_in[3];
    const float* w2  = (const float*)d_in[4];
    const float* b2  = (const float*)d_in[5];
    const float* w3  = (const float*)d_in[6];
    const float* b3  = (const float*)d_in[7];
    float* out = (float*)d_out;

    // d_out (134.2 MB) doubles as the bf16 a||v buffer [M][1024] until gather.
    unsigned short* av = (unsigned short*)d_out;

    float* ws_f = (float*)d_ws;
    unsigned short* xb = (unsigned short*)ws_f;          // 64 MB  (16777216 floats)
    float* after_xb  = ws_f + 16777216;
    unsigned short* wB = (unsigned short*)after_xb;      // 1 MB   (262144 floats)
    float* biasB     = after_xb + 262144;                // 1024
    float* pd        = biasB + 1024;                     // 8 MB
    float* py        = pd + 2097152;                     // 8 MB
    float* y         = py + 2097152;                     // 1 MB
    float* out_small = y + 262144;                       // 1 MB
    int*   list      = (int*)(out_small + 262144);       // 64 KB
    int*   counts    = list + G_ * LSTRIDE;              // 256 B

    hipLaunchKernelGGL(cast_x, dim3(32768), dim3(256), 0, stream, x, xb);
    hipLaunchKernelGGL(cast_w, dim3(512), dim3(256), 0, stream, w1, b1, w2, b2, wB, biasB);
    hipLaunchKernelGGL(build_lists2, dim3(G_), dim3(256), 0, stream, ids, counts, list);
    hipLaunchKernelGGL(gemm12_mfma, dim3(M_ / 128, NF / 128), dim3(256), 0, stream,
                       xb, wB, biasB, av);
    hipLaunchKernelGGL(softaggA, dim3(G_, B_, SPLIT), dim3(256), 0, stream,
                       av, counts, list, pd, py);
    hipLaunchKernelGGL(combineB, dim3(G_, B_), dim3(256), 0, stream, pd, py, y);
    hipLaunchKernelGGL(gemm3, dim3(8, 8), dim3(256), 0, stream, y, w3, b3, out_small);
    hipLaunchKernelGGL(gather_out, dim3(32768), dim3(256), 0, stream, ids, out_small, out);
}

// Round 3
// 225.349 us; speedup vs baseline: 6.6660x; 1.1074x over previous
//
#include <hip/hip_runtime.h>
#include <hip/hip_bf16.h>
#include <math.h>

#define B_ 8
#define N_ 8192
#define D_ 512
#define G_ 64
#define M_ (B_ * N_)   // 65536
#define NF 1024        // fused output dim: cols 0..511 = a, 512..1023 = v
#define SPLIT 8
#define LSTRIDE 256

typedef short bf16x8 __attribute__((ext_vector_type(8)));
typedef float f32x4 __attribute__((ext_vector_type(4)));

__device__ __forceinline__ unsigned short f2bf(float f) {
    __hip_bfloat16 h = __float2bfloat16(f);
    return *reinterpret_cast<unsigned short*>(&h);
}
__device__ __forceinline__ float bf2f(unsigned int bits16) {
    return __uint_as_float(bits16 << 16);
}
__device__ __forceinline__ void gload_lds16(const void* g, void* l) {
    __builtin_amdgcn_global_load_lds((const __attribute__((address_space(1))) void*)g,
                                     (__attribute__((address_space(3))) void*)l,
                                     16, 0, 0);
}

// ---------------- cast kernels ---------------------------------------------
__global__ __launch_bounds__(256) void cast_x(const float* __restrict__ x,
                                              unsigned short* __restrict__ xb) {
    size_t t = (size_t)blockIdx.x * 256 + threadIdx.x;   // one float4
    float4 f = *(const float4*)(x + t * 4);
    ushort4 u;
    u.x = f2bf(f.x); u.y = f2bf(f.y); u.z = f2bf(f.z); u.w = f2bf(f.w);
    *(ushort4*)(xb + t * 4) = u;
}

__global__ __launch_bounds__(256) void cast_w(const float* __restrict__ w1,
                                              const float* __restrict__ b1,
                                              const float* __restrict__ w2,
                                              const float* __restrict__ b2,
                                              unsigned short* __restrict__ wB,
                                              float* __restrict__ biasB) {
    int t = blockIdx.x * 256 + threadIdx.x;   // 0..131071, one float4
    int idx = t * 4;
    int row = idx >> 9;
    int col = idx & 511;
    const float* src = (row < 512) ? (w1 + (size_t)row * 512 + col)
                                   : (w2 + (size_t)(row - 512) * 512 + col);
    float4 f = *(const float4*)src;
    ushort4 u;
    u.x = f2bf(f.x); u.y = f2bf(f.y); u.z = f2bf(f.z); u.w = f2bf(f.w);
    *(ushort4*)(wB + idx) = u;
    if (t < 1024) biasB[t] = (t < 512) ? b1[t] : b2[t - 512];
}

// ---------------- group member lists (one block per group) ------------------
__global__ __launch_bounds__(256) void build_lists2(const int* __restrict__ ids,
                                                    int* __restrict__ counts,
                                                    int* __restrict__ list) {
    __shared__ int sid[N_];     // 32 KB
    __shared__ int scnt[256];
    const int g = blockIdx.x;
    const int t = threadIdx.x;
    for (int i = t; i < N_; i += 256) sid[i] = ids[i];
    __syncthreads();
    int c = 0;
    const int nb = t * 32;
#pragma unroll 8
    for (int k = 0; k < 32; ++k) c += (sid[nb + k] == g) ? 1 : 0;
    scnt[t] = c;
    __syncthreads();
    if (t == 0) {
        int run = 0;
        for (int i = 0; i < 256; ++i) { int x = scnt[i]; scnt[i] = run; run += x; }
        counts[g] = run;
    }
    __syncthreads();
    int pos = g * LSTRIDE + scnt[t];
    for (int k = 0; k < 32; ++k)
        if (sid[nb + k] == g) list[pos++] = nb + k;
}

// ---------------- fused MFMA GEMM: av = [x @ w1^T+b1 || x @ w2^T+b2] (bf16) -
// M=65536, N=1024, K=512. 128x128 tile, BK=64, double-buffered prefetch,
// LDS-staged coalesced epilogue. Block-id swizzle: 8 blocks sharing an A-tile
// are consecutive and congruent mod 8 (same XCD L2).
__global__ __launch_bounds__(256) void gemm12_mfma(const unsigned short* __restrict__ xb,
                                                   const unsigned short* __restrict__ wB,
                                                   const float* __restrict__ biasB,
                                                   unsigned short* __restrict__ av) {
    __shared__ unsigned short ls[2][2][128 * 64];   // 64 KB: [buf][A/B][row*64+k]

    const int o    = blockIdx.x;           // 0..4095
    const int rX   = o & 7;                // xcd slot = m_tile % 8
    const int slot = o >> 3;               // 0..511
    const int n_t  = slot & 7;             // 0..7
    const int m_t  = (slot >> 3) * 8 + rX; // 0..511
    const int m0 = m_t * 128;
    const int n0 = n_t * 128;

    const int tid = threadIdx.x;
    const int l = tid & 63;
    const int w = tid >> 6;            // wave 0..3
    const int wm = w >> 1, wn = w & 1; // 2x2 wave grid, 64x64 per wave

    const int lr = l >> 3;            // staging: row within 8-row chunk
    const int lc = (l & 7) * 8;       // staging: elem col

    const int fr = l & 15;            // fragment row/col
    const int ko = (l >> 4) * 8;
    const int r4 = (l >> 4) * 4;

    f32x4 acc[4][4];
#pragma unroll
    for (int i = 0; i < 4; ++i)
#pragma unroll
        for (int j = 0; j < 4; ++j) acc[i][j] = (f32x4){0.f, 0.f, 0.f, 0.f};

    auto stageT = [&](int buf, int kt) {
#pragma unroll
        for (int q = 0; q < 4; ++q) {
            const int c = w * 4 + q;
            const int row = c * 8 + lr;
            gload_lds16(xb + (size_t)(m0 + row) * 512 + kt + lc, &ls[buf][0][c * 512]);
            gload_lds16(wB + (size_t)(n0 + row) * 512 + kt + lc, &ls[buf][1][c * 512]);
        }
    };

    stageT(0, 0);
    __syncthreads();                   // drain prologue stage
    int cur = 0;
    for (int t = 0; t < 8; ++t) {
        if (t < 7) stageT(cur ^ 1, (t + 1) * 64);   // async prefetch next K-tile
        // compute current K-tile
#pragma unroll
        for (int ks = 0; ks < 2; ++ks) {
            bf16x8 af[4], bfr[4];
#pragma unroll
            for (int i = 0; i < 4; ++i)
                af[i] = *(const bf16x8*)&ls[cur][0][(wm * 64 + i * 16 + fr) * 64 + ks * 32 + ko];
#pragma unroll
            for (int j = 0; j < 4; ++j)
                bfr[j] = *(const bf16x8*)&ls[cur][1][(wn * 64 + j * 16 + fr) * 64 + ks * 32 + ko];
#pragma unroll
            for (int i = 0; i < 4; ++i)
#pragma unroll
                for (int j = 0; j < 4; ++j)
                    acc[i][j] = __builtin_amdgcn_mfma_f32_16x16x32_bf16(af[i], bfr[j], acc[i][j], 0, 0, 0);
        }
        __syncthreads();               // drains prefetch vmcnt + ds reads, swap safe
        cur ^= 1;
    }

    // ---- epilogue: bias + bf16, LDS-staged coalesced store ----
    // tile[row][colByte ^ swz(row)] over first 32KB of ls
    unsigned short* tf = &ls[0][0][0];
#pragma unroll
    for (int j = 0; j < 4; ++j) {
        const int lcol = wn * 64 + j * 16 + fr;
        const float bj = biasB[n0 + lcol];
#pragma unroll
        for (int i = 0; i < 4; ++i) {
            const int lrow0 = wm * 64 + i * 16 + r4;
#pragma unroll
            for (int rr2 = 0; rr2 < 4; ++rr2) {
                const int row = lrow0 + rr2;
                const int byteOff = row * 256 + ((lcol * 2) ^ (((row >> 2) & 7) << 5));
                tf[byteOff >> 1] = f2bf(acc[i][j][rr2] + bj);
            }
        }
    }
    __syncthreads();
#pragma unroll
    for (int p = 0; p < 8; ++p) {
        const int row = p * 16 + (tid >> 4);
        const int cc = (tid & 15) * 8;               // element col, 16B chunks
        const int byteOff = row * 256 + ((cc * 2) ^ (((row >> 2) & 7) << 5));
        uint4 val = *(const uint4*)((const char*)tf + byteOff);
        *(uint4*)(av + (size_t)(m0 + row) * NF + n0 + cc) = val;
    }
}

// ---------------- segment softmax (no max; exp-sum), split over rows --------
__global__ __launch_bounds__(256) void softaggA(const unsigned short* __restrict__ av,
                                                const int* __restrict__ counts,
                                                const int* __restrict__ list,
                                                float* __restrict__ pd,
                                                float* __restrict__ py) {
    const int g = blockIdx.x, b = blockIdx.y, s = blockIdx.z;
    const int e0 = threadIdx.x * 2;
    const int cnt = counts[g];
    float d0 = 0.f, d1 = 0.f, y0 = 0.f, y1 = 0.f;
    for (int i = s; i < cnt; i += SPLIT) {
        const int n = list[g * LSTRIDE + i];
        const unsigned short* row = av + (size_t)(b * N_ + n) * NF;
        const unsigned pa = *(const unsigned*)(row + e0);
        const unsigned pv = *(const unsigned*)(row + 512 + e0);
        const float a0 = bf2f(pa & 0xFFFFu);
        const float a1 = __uint_as_float(pa & 0xFFFF0000u);
        const float v0 = bf2f(pv & 0xFFFFu);
        const float v1 = __uint_as_float(pv & 0xFFFF0000u);
        const float ea0 = __expf(a0), ea1 = __expf(a1);
        d0 += ea0; d1 += ea1;
        y0 = fmaf(ea0, v0, y0); y1 = fmaf(ea1, v1, y1);
    }
    const size_t o = (((size_t)s * G_ + g) * B_ + b) * D_ + e0;
    pd[o] = d0; pd[o + 1] = d1;
    py[o] = y0; py[o + 1] = y1;
}

__global__ __launch_bounds__(256) void combineB(const float* __restrict__ pd,
                                                const float* __restrict__ py,
                                                float* __restrict__ y) {
    const int g = blockIdx.x, b = blockIdx.y;
    const int e0 = threadIdx.x * 2;
    float d0 = 0.f, d1 = 0.f, s0 = 0.f, s1 = 0.f;
#pragma unroll
    for (int s = 0; s < SPLIT; ++s) {
        const size_t o = (((size_t)s * G_ + g) * B_ + b) * D_ + e0;
        d0 += pd[o]; d1 += pd[o + 1];
        s0 += py[o]; s1 += py[o + 1];
    }
    const size_t yo = ((size_t)b * G_ + g) * D_ + e0;
    y[yo] = s0 / d0;
    y[yo + 1] = s1 / d1;
}

// ---------------- small GEMM: out_small = y @ w3^T + b3 (f32 vector) --------
__global__ __launch_bounds__(256) void gemm3(const float* __restrict__ y,
                                             const float* __restrict__ w3,
                                             const float* __restrict__ b3,
                                             float* __restrict__ out_small) {
    __shared__ float ys[16][68];
    __shared__ float wss[16][68];
    const int m0 = blockIdx.x * 64;
    const int n0 = blockIdx.y * 64;
    const int tid = threadIdx.x;
    const int tr = tid >> 4;
    const int tc = tid & 15;
    const int lrow = tid >> 2;
    const int lk4 = (tid & 3) * 4;

    float acc[4][4] = {};

    for (int k0 = 0; k0 < D_; k0 += 16) {
        float4 yv = *(const float4*)(y + (size_t)(m0 + lrow) * D_ + k0 + lk4);
        float4 wv = *(const float4*)(w3 + (size_t)(n0 + lrow) * D_ + k0 + lk4);
        __syncthreads();
        ys[lk4 + 0][lrow] = yv.x;  ys[lk4 + 1][lrow] = yv.y;
        ys[lk4 + 2][lrow] = yv.z;  ys[lk4 + 3][lrow] = yv.w;
        wss[lk4 + 0][lrow] = wv.x; wss[lk4 + 1][lrow] = wv.y;
        wss[lk4 + 2][lrow] = wv.z; wss[lk4 + 3][lrow] = wv.w;
        __syncthreads();
#pragma unroll
        for (int kk = 0; kk < 16; ++kk) {
            float4 y4 = *(const float4*)&ys[kk][tr * 4];
            float4 w4 = *(const float4*)&wss[kk][tc * 4];
            float ya[4] = {y4.x, y4.y, y4.z, y4.w};
            float wa[4] = {w4.x, w4.y, w4.z, w4.w};
#pragma unroll
            for (int i = 0; i < 4; ++i)
#pragma unroll
                for (int j = 0; j < 4; ++j)
                    acc[i][j] = fmaf(ya[i], wa[j], acc[i][j]);
        }
    }

    float bb[4];
#pragma unroll
    for (int j = 0; j < 4; ++j) bb[j] = b3[n0 + tc * 4 + j];
#pragma unroll
    for (int i = 0; i < 4; ++i) {
        size_t o = (size_t)(m0 + tr * 4 + i) * D_ + n0 + tc * 4;
        float4 r;
        r.x = acc[i][0] + bb[0]; r.y = acc[i][1] + bb[1];
        r.z = acc[i][2] + bb[2]; r.w = acc[i][3] + bb[3];
        *(float4*)(out_small + o) = r;
    }
}

// ---------------- gather group outputs back to rows -------------------------
__global__ __launch_bounds__(256) void gather_out(const int* __restrict__ ids,
                                                  const float* __restrict__ out_small,
                                                  float* __restrict__ out) {
    const int c = blockIdx.x * 256 + threadIdx.x;   // one float4 chunk
    const int per_row = D_ / 4;                     // 128
    const int b = c / (N_ * per_row);
    const int rem = c % (N_ * per_row);
    const int n = rem / per_row;
    const int q = rem % per_row;
    const int g = ids[n];
    float4 val = *(const float4*)(out_small + ((size_t)b * G_ + g) * D_ + q * 4);
    *(float4*)(out + (size_t)c * 4) = val;
}

// ---------------- launcher --------------------------------------------------
extern "C" void kernel_launch(void* const* d_in, const int* in_sizes, int n_in,
                              void* d_out, int out_size, void* d_ws, size_t ws_size,
                              hipStream_t stream) {
    (void)in_sizes; (void)n_in; (void)out_size; (void)ws_size;
    const float* x   = (const float*)d_in[0];
    const int*   ids = (const int*)d_in[1];
    const float* w1  = (const float*)d_in[2];
    const float* b1  = (const float*)d_in[3];
    const float* w2  = (const float*)d_in[4];
    const float* b2  = (const float*)d_in[5];
    const float* w3  = (const float*)d_in[6];
    const float* b3  = (const float*)d_in[7];
    float* out = (float*)d_out;

    // d_out (134 MB) doubles as the bf16 a||v buffer [M][1024] until gather.
    unsigned short* av = (unsigned short*)d_out;

    float* ws_f = (float*)d_ws;
    unsigned short* xb = (unsigned short*)ws_f;          // 64 MB
    float* after_xb  = ws_f + 16777216;
    unsigned short* wB = (unsigned short*)after_xb;      // 1 MB
    float* biasB     = after_xb + 262144;                // 1024
    float* pd        = biasB + 1024;                     // 8 MB
    float* py        = pd + 2097152;                     // 8 MB
    float* y         = py + 2097152;                     // 1 MB
    float* out_small = y + 262144;                       // 1 MB
    int*   list      = (int*)(out_small + 262144);       // 64 KB
    int*   counts    = list + G_ * LSTRIDE;              // 256 B

    hipLaunchKernelGGL(cast_x, dim3(32768), dim3(256), 0, stream, x, xb);
    hipLaunchKernelGGL(cast_w, dim3(512), dim3(256), 0, stream, w1, b1, w2, b2, wB, biasB);
    hipLaunchKernelGGL(build_lists2, dim3(G_), dim3(256), 0, stream, ids, counts, list);
    hipLaunchKernelGGL(gemm12_mfma, dim3(4096), dim3(256), 0, stream, xb, wB, biasB, av);
    hipLaunchKernelGGL(softaggA, dim3(G_, B_, SPLIT), dim3(256), 0, stream,
                       av, counts, list, pd, py);
    hipLaunchKernelGGL(combineB, dim3(G_, B_), dim3(256), 0, stream, pd, py, y);
    hipLaunchKernelGGL(gemm3, dim3(8, 8), dim3(256), 0, stream, y, w3, b3, out_small);
    hipLaunchKernelGGL(gather_out, dim3(32768), dim3(256), 0, stream, ids, out_small, out);
}

// Round 4
// 216.405 us; speedup vs baseline: 6.9415x; 1.0413x over previous
//
#include <hip/hip_runtime.h>
#include <hip/hip_bf16.h>
#include <math.h>

#define B_ 8
#define N_ 8192
#define D_ 512
#define G_ 64
#define M_ (B_ * N_)   // 65536

typedef short bf16x8 __attribute__((ext_vector_type(8)));
typedef float f32x4 __attribute__((ext_vector_type(4)));

__device__ __forceinline__ unsigned short f2bf(float f) {
    __hip_bfloat16 h = __float2bfloat16(f);
    return *reinterpret_cast<unsigned short*>(&h);
}
__device__ __forceinline__ void gload_lds16(const void* g, void* l) {
    __builtin_amdgcn_global_load_lds((const __attribute__((address_space(1))) void*)g,
                                     (__attribute__((address_space(3))) void*)l,
                                     16, 0, 0);
}

// ---------------- cast kernels ---------------------------------------------
__global__ __launch_bounds__(256) void cast_x(const float* __restrict__ x,
                                              unsigned short* __restrict__ xb) {
    size_t t = (size_t)blockIdx.x * 256 + threadIdx.x;   // one float4
    float4 f = *(const float4*)(x + t * 4);
    ushort4 u;
    u.x = f2bf(f.x); u.y = f2bf(f.y); u.z = f2bf(f.z); u.w = f2bf(f.w);
    *(ushort4*)(xb + t * 4) = u;
}

__global__ __launch_bounds__(256) void cast_w(const float* __restrict__ w1,
                                              const float* __restrict__ b1,
                                              const float* __restrict__ w2,
                                              const float* __restrict__ b2,
                                              unsigned short* __restrict__ wB,
                                              float* __restrict__ biasB) {
    int t = blockIdx.x * 256 + threadIdx.x;   // 0..131071, one float4
    int idx = t * 4;
    int row = idx >> 9;
    int col = idx & 511;
    const float* src = (row < 512) ? (w1 + (size_t)row * 512 + col)
                                   : (w2 + (size_t)(row - 512) * 512 + col);
    float4 f = *(const float4*)src;
    ushort4 u;
    u.x = f2bf(f.x); u.y = f2bf(f.y); u.z = f2bf(f.z); u.w = f2bf(f.w);
    *(ushort4*)(wB + idx) = u;
    if (t < 1024) biasB[t] = (t < 512) ? b1[t] : b2[t - 512];
}

// ---------------- group-sorted permutation, bases, tile->first-group --------
__global__ __launch_bounds__(256) void build_lists3(const int* __restrict__ ids,
                                                    int* __restrict__ counts,
                                                    int* __restrict__ baseO,
                                                    int* __restrict__ fgO,
                                                    int* __restrict__ perm) {
    __shared__ int sid[N_];                    // 32 KB
    __shared__ unsigned short hist[256][G_];   // 32 KB
    __shared__ int sbase[G_ + 1];
    const int t = threadIdx.x;
    for (int i = t; i < N_; i += 256) sid[i] = ids[i];
#pragma unroll
    for (int g = 0; g < G_; ++g) hist[t][g] = 0;
    __syncthreads();
    const int nb = t * 32;
    for (int k = 0; k < 32; ++k) hist[t][sid[nb + k]]++;
    __syncthreads();
    if (t < G_) {   // column-wise prefix over thread strips for group t
        int run = 0;
        for (int i = 0; i < 256; ++i) {
            int v = hist[i][t];
            hist[i][t] = (unsigned short)run;
            run += v;
        }
        counts[t] = run;
    }
    __syncthreads();
    if (t == 0) {
        int acc = 0;
        for (int g = 0; g < G_; ++g) { sbase[g] = acc; acc += counts[g]; }
        sbase[G_] = acc;
    }
    __syncthreads();
    if (t < G_) baseO[t] = sbase[t];
    if (t < G_) {   // first group of each 128-row tile
        const int row = t * 128;
        int g = 0;
        while (g + 1 < G_ && sbase[g + 1] <= row) ++g;
        fgO[t] = g;
    }
    // emit permutation (deterministic: strip order, then in-strip order)
    for (int k = 0; k < 32; ++k) {
        const int n = nb + k;
        const int g = sid[n];
        const int pos = sbase[g] + hist[t][g];
        hist[t][g]++;
        perm[pos] = n;
    }
}

// ---------------- fused GEMM + segment softmax-aggregate --------------------
// Per block: 128 permuted rows (one b, one tile) x 64 e-cols.
// acc_a = x@W1^T rows, acc_v = x@W2^T rows; epilogue computes exp(a+b1),
// segment-sums d=sum(e), y=sum(e*(v+b2)) per (group,col) -> partial buffer.
// XOR-swizzled LDS (pre-swizzled global source cols), double-buffered.
__global__ __launch_bounds__(256) void gemm_fused(const unsigned short* __restrict__ xb,
                                                  const unsigned short* __restrict__ wB,
                                                  const float* __restrict__ biasB,
                                                  const int* __restrict__ perm,
                                                  const int* __restrict__ base,
                                                  const int* __restrict__ fg,
                                                  float* __restrict__ pt) {
    __shared__ unsigned short lsA[2][128 * 64];    // 2 x 16 KB
    __shared__ unsigned short lsB[2][2][64 * 64];  // 2 x 2 x 8 KB   (W1, W2 panels)

    // block swizzle: 8 et-blocks sharing an A-tile are same-XCD, 8 apart
    const int o  = blockIdx.x;            // 0..4095
    const int mt = (o & 7) + ((o >> 6) << 3);   // 0..511 global m-tile
    const int et = (o >> 3) & 7;                // 0..7 e-tile (64 cols)
    const int b  = mt >> 6;
    const int tl = mt & 63;
    const int r0 = tl * 128;              // perm-slab row base

    const int tid = threadIdx.x;
    const int l = tid & 63;
    const int w = tid >> 6;
    const int wm = w >> 1, wn = w & 1;    // 2x2 wave grid: rows 64, cols 32
    const int lr = l >> 3;                // staging row-in-chunk
    const int lslot = l & 7;              // staging 16B slot
    const int fr = l & 15;                // fragment row/col
    const int scol = 8 * (lslot ^ lr);    // pre-swizzled source col (elems)

    // per-lane permuted A source rows (fixed across K)
    int nrow[4];
#pragma unroll
    for (int q = 0; q < 4; ++q) nrow[q] = perm[r0 + (w * 4 + q) * 8 + lr];

    f32x4 acc_a[4][2], acc_v[4][2];
#pragma unroll
    for (int i = 0; i < 4; ++i)
#pragma unroll
        for (int j = 0; j < 2; ++j) {
            acc_a[i][j] = (f32x4){0.f, 0.f, 0.f, 0.f};
            acc_v[i][j] = (f32x4){0.f, 0.f, 0.f, 0.f};
        }

    auto stageT = [&](int buf, int kt) {
#pragma unroll
        for (int q = 0; q < 4; ++q) {
            const int c = w * 4 + q;
            gload_lds16(xb + (((size_t)(b << 13) + nrow[q]) << 9) + kt + scol,
                        &lsA[buf][c * 512]);
        }
#pragma unroll
        for (int q = 0; q < 4; ++q) {
            const int p = q >> 1;
            const int c2 = (w << 1) | (q & 1);
            const int wr = p * 512 + et * 64 + c2 * 8 + lr;
            gload_lds16(wB + ((size_t)wr << 9) + kt + scol, &lsB[buf][p][c2 * 512]);
        }
    };

    stageT(0, 0);
    __syncthreads();
    int cur = 0;
    for (int t = 0; t < 8; ++t) {
        if (t < 7) stageT(cur ^ 1, (t + 1) * 64);
#pragma unroll
        for (int ks = 0; ks < 2; ++ks) {
            const int ib = 8 * ((ks * 4 + (l >> 4)) ^ (fr & 7));   // swizzled in-row elems
            bf16x8 af[4], bq[2][2];
#pragma unroll
            for (int i = 0; i < 4; ++i)
                af[i] = *(const bf16x8*)&lsA[cur][(wm * 64 + i * 16 + fr) * 64 + ib];
#pragma unroll
            for (int p = 0; p < 2; ++p)
#pragma unroll
                for (int j = 0; j < 2; ++j)
                    bq[p][j] = *(const bf16x8*)&lsB[cur][p][(wn * 32 + j * 16 + fr) * 64 + ib];
#pragma unroll
            for (int i = 0; i < 4; ++i)
#pragma unroll
                for (int j = 0; j < 2; ++j) {
                    acc_a[i][j] = __builtin_amdgcn_mfma_f32_16x16x32_bf16(af[i], bq[0][j], acc_a[i][j], 0, 0, 0);
                    acc_v[i][j] = __builtin_amdgcn_mfma_f32_16x16x32_bf16(af[i], bq[1][j], acc_v[i][j], 0, 0, 0);
                }
        }
        __syncthreads();
        cur ^= 1;
    }

    // ---- epilogue: exp + segment reduce ----
    const int fg0 = fg[tl];
    const int bnd0 = (fg0 + 1 < G_) ? base[fg0 + 1] : (1 << 30);
    const int bnd1 = (fg0 + 2 < G_) ? base[fg0 + 2] : (1 << 30);
    const int bnd2 = (fg0 + 3 < G_) ? base[fg0 + 3] : (1 << 30);
    float b1c[2], b2c[2];
#pragma unroll
    for (int j = 0; j < 2; ++j) {
        const int col = et * 64 + wn * 32 + j * 16 + fr;
        b1c[j] = biasB[col];
        b2c[j] = biasB[512 + col];
    }
    float dpart[4][2] = {}, ypart[4][2] = {};
    const int rbase = r0 + wm * 64 + ((l >> 4) << 2);
#pragma unroll
    for (int i = 0; i < 4; ++i)
#pragma unroll
        for (int rr = 0; rr < 4; ++rr) {
            const int row = rbase + i * 16 + rr;
            const int s = (row >= bnd0) + (row >= bnd1) + (row >= bnd2);
#pragma unroll
            for (int j = 0; j < 2; ++j) {
                const float e = __expf(acc_a[i][j][rr] + b1c[j]);
                const float ey = e * (acc_v[i][j][rr] + b2c[j]);
#pragma unroll
                for (int s2 = 0; s2 < 4; ++s2) {
                    dpart[s2][j] += (s == s2) ? e : 0.f;
                    ypart[s2][j] += (s == s2) ? ey : 0.f;
                }
            }
        }
    // butterfly over lane bits 4,5 -> sum over the wave's 64 rows
#pragma unroll
    for (int s2 = 0; s2 < 4; ++s2)
#pragma unroll
        for (int j = 0; j < 2; ++j) {
            dpart[s2][j] += __shfl_xor(dpart[s2][j], 16);
            dpart[s2][j] += __shfl_xor(dpart[s2][j], 32);
            ypart[s2][j] += __shfl_xor(ypart[s2][j], 16);
            ypart[s2][j] += __shfl_xor(ypart[s2][j], 32);
        }
    float* red = (float*)&lsA[0][0];    // [wm][s][col64][2] = 4 KB
    if ((l >> 4) == 0) {
#pragma unroll
        for (int s2 = 0; s2 < 4; ++s2)
#pragma unroll
            for (int j = 0; j < 2; ++j) {
                const int colL = wn * 32 + j * 16 + fr;
                red[((wm * 4 + s2) * 64 + colL) * 2 + 0] = dpart[s2][j];
                red[((wm * 4 + s2) * 64 + colL) * 2 + 1] = ypart[s2][j];
            }
    }
    __syncthreads();
#pragma unroll
    for (int k = 0; k < 2; ++k) {
        const int idx = tid * 2 + k;      // 0..511
        const int dy = idx & 1;
        const int colL = (idx >> 1) & 63;
        const int s2 = idx >> 7;
        const float vsum = red[((0 * 4 + s2) * 64 + colL) * 2 + dy] +
                           red[((1 * 4 + s2) * 64 + colL) * 2 + dy];
        pt[((((size_t)(b * 64 + tl)) * 4 + s2) * 512 + et * 64 + colL) * 2 + dy] = vsum;
    }
}

// ---------------- ordered cross-tile combine -> y[b][g][col] ----------------
__global__ __launch_bounds__(256) void combineC(const float* __restrict__ pt,
                                                const int* __restrict__ base,
                                                const int* __restrict__ counts,
                                                const int* __restrict__ fg,
                                                float* __restrict__ y) {
    const int g = blockIdx.x, b = blockIdx.y;
    const int bs = base[g];
    int cnt = counts[g];
    if (cnt == 0) cnt = 1;
    const int t0 = bs >> 7, t1 = (bs + cnt - 1) >> 7;
    for (int c = threadIdx.x; c < 512; c += 256) {
        float d = 0.f, yy = 0.f;
        for (int t = t0; t <= t1; ++t) {
            const int s = g - fg[t];
            if (s >= 0 && s < 4) {
                const float* p = &pt[((((size_t)(b * 64 + t)) * 4 + s) * 512 + c) * 2];
                d += p[0];
                yy += p[1];
            }
        }
        y[((size_t)(b * G_ + g)) * 512 + c] = yy / d;
    }
}

// ---------------- small GEMM: out_small = y @ w3^T + b3 (f32 vector) --------
__global__ __launch_bounds__(256) void gemm3(const float* __restrict__ y,
                                             const float* __restrict__ w3,
                                             const float* __restrict__ b3,
                                             float* __restrict__ out_small) {
    __shared__ float ys[16][68];
    __shared__ float wss[16][68];
    const int m0 = blockIdx.x * 64;
    const int n0 = blockIdx.y * 64;
    const int tid = threadIdx.x;
    const int tr = tid >> 4;
    const int tc = tid & 15;
    const int lrow = tid >> 2;
    const int lk4 = (tid & 3) * 4;

    float acc[4][4] = {};

    for (int k0 = 0; k0 < D_; k0 += 16) {
        float4 yv = *(const float4*)(y + (size_t)(m0 + lrow) * D_ + k0 + lk4);
        float4 wv = *(const float4*)(w3 + (size_t)(n0 + lrow) * D_ + k0 + lk4);
        __syncthreads();
        ys[lk4 + 0][lrow] = yv.x;  ys[lk4 + 1][lrow] = yv.y;
        ys[lk4 + 2][lrow] = yv.z;  ys[lk4 + 3][lrow] = yv.w;
        wss[lk4 + 0][lrow] = wv.x; wss[lk4 + 1][lrow] = wv.y;
        wss[lk4 + 2][lrow] = wv.z; wss[lk4 + 3][lrow] = wv.w;
        __syncthreads();
#pragma unroll
        for (int kk = 0; kk < 16; ++kk) {
            float4 y4 = *(const float4*)&ys[kk][tr * 4];
            float4 w4 = *(const float4*)&wss[kk][tc * 4];
            float ya[4] = {y4.x, y4.y, y4.z, y4.w};
            float wa[4] = {w4.x, w4.y, w4.z, w4.w};
#pragma unroll
            for (int i = 0; i < 4; ++i)
#pragma unroll
                for (int j = 0; j < 4; ++j)
                    acc[i][j] = fmaf(ya[i], wa[j], acc[i][j]);
        }
    }

    float bb[4];
#pragma unroll
    for (int j = 0; j < 4; ++j) bb[j] = b3[n0 + tc * 4 + j];
#pragma unroll
    for (int i = 0; i < 4; ++i) {
        size_t o = (size_t)(m0 + tr * 4 + i) * D_ + n0 + tc * 4;
        float4 r;
        r.x = acc[i][0] + bb[0]; r.y = acc[i][1] + bb[1];
        r.z = acc[i][2] + bb[2]; r.w = acc[i][3] + bb[3];
        *(float4*)(out_small + o) = r;
    }
}

// ---------------- gather group outputs back to rows -------------------------
__global__ __launch_bounds__(256) void gather_out(const int* __restrict__ ids,
                                                  const float* __restrict__ out_small,
                                                  float* __restrict__ out) {
    const int c = blockIdx.x * 256 + threadIdx.x;   // one float4 chunk
    const int per_row = D_ / 4;                     // 128
    const int b = c / (N_ * per_row);
    const int rem = c % (N_ * per_row);
    const int n = rem / per_row;
    const int q = rem % per_row;
    const int g = ids[n];
    float4 val = *(const float4*)(out_small + ((size_t)b * G_ + g) * D_ + q * 4);
    *(float4*)(out + (size_t)c * 4) = val;
}

// ---------------- launcher --------------------------------------------------
extern "C" void kernel_launch(void* const* d_in, const int* in_sizes, int n_in,
                              void* d_out, int out_size, void* d_ws, size_t ws_size,
                              hipStream_t stream) {
    (void)in_sizes; (void)n_in; (void)out_size; (void)ws_size;
    const float* x   = (const float*)d_in[0];
    const int*   ids = (const int*)d_in[1];
    const float* w1  = (const float*)d_in[2];
    const float* b1  = (const float*)d_in[3];
    const float* w2  = (const float*)d_in[4];
    const float* b2  = (const float*)d_in[5];
    const float* w3  = (const float*)d_in[6];
    const float* b3  = (const float*)d_in[7];
    float* out = (float*)d_out;

    float* ws_f = (float*)d_ws;
    unsigned short* xb = (unsigned short*)ws_f;          // 64 MB
    float* after_xb  = ws_f + 16777216;
    unsigned short* wB = (unsigned short*)after_xb;      // 1 MB
    float* biasB     = after_xb + 262144;                // 4 KB
    float* pt        = biasB + 1024;                     // 8 MB  [b][tl][s4][512][2]
    float* y         = pt + 2097152;                     // 1 MB
    float* out_small = y + 262144;                       // 1 MB
    int*   perm      = (int*)(out_small + 262144);       // 32 KB
    int*   base      = perm + N_;
    int*   counts    = base + G_;
    int*   fg        = counts + G_;

    hipLaunchKernelGGL(cast_x, dim3(32768), dim3(256), 0, stream, x, xb);
    hipLaunchKernelGGL(cast_w, dim3(512), dim3(256), 0, stream, w1, b1, w2, b2, wB, biasB);
    hipLaunchKernelGGL(build_lists3, dim3(1), dim3(256), 0, stream, ids, counts, base, fg, perm);
    hipLaunchKernelGGL(gemm_fused, dim3(4096), dim3(256), 0, stream,
                       xb, wB, biasB, perm, base, fg, pt);
    hipLaunchKernelGGL(combineC, dim3(G_, B_), dim3(256), 0, stream, pt, base, counts, fg, y);
    hipLaunchKernelGGL(gemm3, dim3(8, 8), dim3(256), 0, stream, y, w3, b3, out_small);
    hipLaunchKernelGGL(gather_out, dim3(32768), dim3(256), 0, stream, ids, out_small, out);
}

// Round 5
// 212.272 us; speedup vs baseline: 7.0767x; 1.0195x over previous
//
#include <hip/hip_runtime.h>
#include <hip/hip_bf16.h>
#include <math.h>

#define B_ 8
#define N_ 8192
#define D_ 512
#define G_ 64
#define M_ (B_ * N_)   // 65536

typedef short bf16x8 __attribute__((ext_vector_type(8)));
typedef float f32x4 __attribute__((ext_vector_type(4)));

__device__ __forceinline__ unsigned short f2bf(float f) {
    __hip_bfloat16 h = __float2bfloat16(f);
    return *reinterpret_cast<unsigned short*>(&h);
}
__device__ __forceinline__ void gload_lds16(const void* g, void* l) {
    __builtin_amdgcn_global_load_lds((const __attribute__((address_space(1))) void*)g,
                                     (__attribute__((address_space(3))) void*)l,
                                     16, 0, 0);
}

// ---------------- cast kernel (weights only; x is consumed f32 directly) ----
__global__ __launch_bounds__(256) void cast_w(const float* __restrict__ w1,
                                              const float* __restrict__ b1,
                                              const float* __restrict__ w2,
                                              const float* __restrict__ b2,
                                              unsigned short* __restrict__ wB,
                                              float* __restrict__ biasB) {
    int t = blockIdx.x * 256 + threadIdx.x;   // 0..131071, one float4
    int idx = t * 4;
    int row = idx >> 9;
    int col = idx & 511;
    const float* src = (row < 512) ? (w1 + (size_t)row * 512 + col)
                                   : (w2 + (size_t)(row - 512) * 512 + col);
    float4 f = *(const float4*)src;
    ushort4 u;
    u.x = f2bf(f.x); u.y = f2bf(f.y); u.z = f2bf(f.z); u.w = f2bf(f.w);
    *(ushort4*)(wB + idx) = u;
    if (t < 1024) biasB[t] = (t < 512) ? b1[t] : b2[t - 512];
}

// ---------------- group-sorted permutation, bases, tile->first-group --------
__global__ __launch_bounds__(256) void build_lists3(const int* __restrict__ ids,
                                                    int* __restrict__ counts,
                                                    int* __restrict__ baseO,
                                                    int* __restrict__ fgO,
                                                    int* __restrict__ perm) {
    __shared__ int sid[N_];                    // 32 KB
    __shared__ unsigned short hist[256][G_];   // 32 KB
    __shared__ int sbase[G_ + 1];
    const int t = threadIdx.x;
    for (int i = t; i < N_; i += 256) sid[i] = ids[i];
#pragma unroll
    for (int g = 0; g < G_; ++g) hist[t][g] = 0;
    __syncthreads();
    const int nb = t * 32;
    for (int k = 0; k < 32; ++k) hist[t][sid[nb + k]]++;
    __syncthreads();
    if (t < G_) {   // column-wise prefix over thread strips for group t
        int run = 0;
        for (int i = 0; i < 256; ++i) {
            int v = hist[i][t];
            hist[i][t] = (unsigned short)run;
            run += v;
        }
        counts[t] = run;
    }
    __syncthreads();
    if (t == 0) {
        int acc = 0;
        for (int g = 0; g < G_; ++g) { sbase[g] = acc; acc += counts[g]; }
        sbase[G_] = acc;
    }
    __syncthreads();
    if (t < G_) baseO[t] = sbase[t];
    if (t < G_) {   // first group of each 128-row tile
        const int row = t * 128;
        int g = 0;
        while (g + 1 < G_ && sbase[g + 1] <= row) ++g;
        fgO[t] = g;
    }
    // emit permutation (deterministic: strip order, then in-strip order)
    for (int k = 0; k < 32; ++k) {
        const int n = nb + k;
        const int g = sid[n];
        const int pos = sbase[g] + hist[t][g];
        hist[t][g]++;
        perm[pos] = n;
    }
}

// ---------------- fused GEMM + segment softmax-aggregate --------------------
// Per block: 128 permuted rows (one b, one tile) x 64 e-cols.
// A is reg-staged from f32 x (load f32 -> cvt bf16 -> swizzled ds_write),
// loads issued at iteration top so HBM latency hides under current MFMAs.
// B panels staged via global_load_lds with pre-swizzled source cols.
__global__ __launch_bounds__(256) void gemm_fused(const float* __restrict__ x,
                                                  const unsigned short* __restrict__ wB,
                                                  const float* __restrict__ biasB,
                                                  const int* __restrict__ perm,
                                                  const int* __restrict__ base,
                                                  const int* __restrict__ fg,
                                                  float* __restrict__ pt) {
    __shared__ unsigned short lsA[2][128 * 64];    // 2 x 16 KB
    __shared__ unsigned short lsB[2][2][64 * 64];  // 2 x 2 x 8 KB   (W1, W2 panels)

    // block swizzle: 8 et-blocks sharing an A-tile are same-XCD, 8 apart
    const int o  = blockIdx.x;            // 0..4095
    const int mt = (o & 7) + ((o >> 6) << 3);   // 0..511 global m-tile
    const int et = (o >> 3) & 7;                // 0..7 e-tile (64 cols)
    const int b  = mt >> 6;
    const int tl = mt & 63;
    const int r0 = tl * 128;              // perm-slab row base

    const int tid = threadIdx.x;
    const int l = tid & 63;
    const int w = tid >> 6;
    const int wm = w >> 1, wn = w & 1;    // 2x2 wave grid: rows 64, cols 32
    const int lr = l >> 3;                // staging row-in-chunk
    const int lslot = l & 7;              // staging 16B slot
    const int fr = l & 15;                // fragment row/col
    const int scol = 8 * (lslot ^ lr);    // pre-swizzled source col (elems)

    // per-lane permuted A source rows (fixed across K)
    int nrow[4];
#pragma unroll
    for (int q = 0; q < 4; ++q) nrow[q] = perm[r0 + (w * 4 + q) * 8 + lr];

    f32x4 acc_a[4][2], acc_v[4][2];
#pragma unroll
    for (int i = 0; i < 4; ++i)
#pragma unroll
        for (int j = 0; j < 2; ++j) {
            acc_a[i][j] = (f32x4){0.f, 0.f, 0.f, 0.f};
            acc_v[i][j] = (f32x4){0.f, 0.f, 0.f, 0.f};
        }

    float4 areg[8];
    auto loadA = [&](int kt) {   // issue 8 global f32x4 loads for tile kt
#pragma unroll
        for (int q = 0; q < 4; ++q) {
            const float* src = x + (((size_t)(b << 13) + nrow[q]) << 9) + kt + scol;
            areg[q * 2]     = *(const float4*)src;
            areg[q * 2 + 1] = *(const float4*)(src + 4);
        }
    };
    auto writeA = [&](int buf) { // cvt + swizzled ds_write (same image as gload_lds)
#pragma unroll
        for (int q = 0; q < 4; ++q) {
            const int c = w * 4 + q;
            union { unsigned short us[8]; uint4 v4; } pk;
            const float* f = (const float*)&areg[q * 2];
#pragma unroll
            for (int e = 0; e < 8; ++e) pk.us[e] = f2bf(f[e]);
            *(uint4*)((char*)&lsA[buf][0] + c * 1024 + l * 16) = pk.v4;
        }
    };
    auto stageB = [&](int buf, int kt) {
#pragma unroll
        for (int q = 0; q < 4; ++q) {
            const int p = q >> 1;
            const int c2 = (w << 1) | (q & 1);
            const int wr = p * 512 + et * 64 + c2 * 8 + lr;
            gload_lds16(wB + ((size_t)wr << 9) + kt + scol, &lsB[buf][p][c2 * 512]);
        }
    };

    loadA(0);
    stageB(0, 0);
    writeA(0);
    __syncthreads();
    int cur = 0;
    for (int t = 0; t < 8; ++t) {
        if (t < 7) { loadA((t + 1) * 64); stageB(cur ^ 1, (t + 1) * 64); }
#pragma unroll
        for (int ks = 0; ks < 2; ++ks) {
            const int ib = 8 * ((ks * 4 + (l >> 4)) ^ (fr & 7));   // swizzled in-row elems
            bf16x8 af[4], bq[2][2];
#pragma unroll
            for (int i = 0; i < 4; ++i)
                af[i] = *(const bf16x8*)&lsA[cur][(wm * 64 + i * 16 + fr) * 64 + ib];
#pragma unroll
            for (int p = 0; p < 2; ++p)
#pragma unroll
                for (int j = 0; j < 2; ++j)
                    bq[p][j] = *(const bf16x8*)&lsB[cur][p][(wn * 32 + j * 16 + fr) * 64 + ib];
#pragma unroll
            for (int i = 0; i < 4; ++i)
#pragma unroll
                for (int j = 0; j < 2; ++j) {
                    acc_a[i][j] = __builtin_amdgcn_mfma_f32_16x16x32_bf16(af[i], bq[0][j], acc_a[i][j], 0, 0, 0);
                    acc_v[i][j] = __builtin_amdgcn_mfma_f32_16x16x32_bf16(af[i], bq[1][j], acc_v[i][j], 0, 0, 0);
                }
        }
        if (t < 7) writeA(cur ^ 1);   // waits A-loads (vmcnt), B gloads stay in flight
        __syncthreads();
        cur ^= 1;
    }

    // ---- epilogue: exp + segment reduce ----
    const int fg0 = fg[tl];
    const int bnd0 = (fg0 + 1 < G_) ? base[fg0 + 1] : (1 << 30);
    const int bnd1 = (fg0 + 2 < G_) ? base[fg0 + 2] : (1 << 30);
    const int bnd2 = (fg0 + 3 < G_) ? base[fg0 + 3] : (1 << 30);
    float b1c[2], b2c[2];
#pragma unroll
    for (int j = 0; j < 2; ++j) {
        const int col = et * 64 + wn * 32 + j * 16 + fr;
        b1c[j] = biasB[col];
        b2c[j] = biasB[512 + col];
    }
    float dpart[4][2] = {}, ypart[4][2] = {};
    const int rbase = r0 + wm * 64 + ((l >> 4) << 2);
#pragma unroll
    for (int i = 0; i < 4; ++i)
#pragma unroll
        for (int rr = 0; rr < 4; ++rr) {
            const int row = rbase + i * 16 + rr;
            const int s = (row >= bnd0) + (row >= bnd1) + (row >= bnd2);
#pragma unroll
            for (int j = 0; j < 2; ++j) {
                const float e = __expf(acc_a[i][j][rr] + b1c[j]);
                const float ey = e * (acc_v[i][j][rr] + b2c[j]);
#pragma unroll
                for (int s2 = 0; s2 < 4; ++s2) {
                    dpart[s2][j] += (s == s2) ? e : 0.f;
                    ypart[s2][j] += (s == s2) ? ey : 0.f;
                }
            }
        }
    // butterfly over lane bits 4,5 -> sum over the wave's 64 rows
#pragma unroll
    for (int s2 = 0; s2 < 4; ++s2)
#pragma unroll
        for (int j = 0; j < 2; ++j) {
            dpart[s2][j] += __shfl_xor(dpart[s2][j], 16);
            dpart[s2][j] += __shfl_xor(dpart[s2][j], 32);
            ypart[s2][j] += __shfl_xor(ypart[s2][j], 16);
            ypart[s2][j] += __shfl_xor(ypart[s2][j], 32);
        }
    float* red = (float*)&lsA[0][0];    // [wm][s][col64][2] = 4 KB
    if ((l >> 4) == 0) {
#pragma unroll
        for (int s2 = 0; s2 < 4; ++s2)
#pragma unroll
            for (int j = 0; j < 2; ++j) {
                const int colL = wn * 32 + j * 16 + fr;
                red[((wm * 4 + s2) * 64 + colL) * 2 + 0] = dpart[s2][j];
                red[((wm * 4 + s2) * 64 + colL) * 2 + 1] = ypart[s2][j];
            }
    }
    __syncthreads();
#pragma unroll
    for (int k = 0; k < 2; ++k) {
        const int idx = tid * 2 + k;      // 0..511
        const int dy = idx & 1;
        const int colL = (idx >> 1) & 63;
        const int s2 = idx >> 7;
        const float vsum = red[((0 * 4 + s2) * 64 + colL) * 2 + dy] +
                           red[((1 * 4 + s2) * 64 + colL) * 2 + dy];
        pt[((((size_t)(b * 64 + tl)) * 4 + s2) * 512 + et * 64 + colL) * 2 + dy] = vsum;
    }
}

// ---------------- ordered cross-tile combine -> y[b][g][col] ----------------
__global__ __launch_bounds__(256) void combineC(const float* __restrict__ pt,
                                                const int* __restrict__ base,
                                                const int* __restrict__ counts,
                                                const int* __restrict__ fg,
                                                float* __restrict__ y) {
    const int g = blockIdx.x, b = blockIdx.y;
    const int bs = base[g];
    int cnt = counts[g];
    if (cnt == 0) cnt = 1;
    const int t0 = bs >> 7, t1 = (bs + cnt - 1) >> 7;
    for (int c = threadIdx.x; c < 512; c += 256) {
        float d = 0.f, yy = 0.f;
        for (int t = t0; t <= t1; ++t) {
            const int s = g - fg[t];
            if (s >= 0 && s < 4) {
                const float* p = &pt[((((size_t)(b * 64 + t)) * 4 + s) * 512 + c) * 2];
                d += p[0];
                yy += p[1];
            }
        }
        y[((size_t)(b * G_ + g)) * 512 + c] = yy / d;
    }
}

// ---------------- small GEMM: out_small = y @ w3^T + b3 (f32 vector) --------
__global__ __launch_bounds__(256) void gemm3(const float* __restrict__ y,
                                             const float* __restrict__ w3,
                                             const float* __restrict__ b3,
                                             float* __restrict__ out_small) {
    __shared__ float ys[16][68];
    __shared__ float wss[16][68];
    const int m0 = blockIdx.x * 64;
    const int n0 = blockIdx.y * 64;
    const int tid = threadIdx.x;
    const int tr = tid >> 4;
    const int tc = tid & 15;
    const int lrow = tid >> 2;
    const int lk4 = (tid & 3) * 4;

    float acc[4][4] = {};

    for (int k0 = 0; k0 < D_; k0 += 16) {
        float4 yv = *(const float4*)(y + (size_t)(m0 + lrow) * D_ + k0 + lk4);
        float4 wv = *(const float4*)(w3 + (size_t)(n0 + lrow) * D_ + k0 + lk4);
        __syncthreads();
        ys[lk4 + 0][lrow] = yv.x;  ys[lk4 + 1][lrow] = yv.y;
        ys[lk4 + 2][lrow] = yv.z;  ys[lk4 + 3][lrow] = yv.w;
        wss[lk4 + 0][lrow] = wv.x; wss[lk4 + 1][lrow] = wv.y;
        wss[lk4 + 2][lrow] = wv.z; wss[lk4 + 3][lrow] = wv.w;
        __syncthreads();
#pragma unroll
        for (int kk = 0; kk < 16; ++kk) {
            float4 y4 = *(const float4*)&ys[kk][tr * 4];
            float4 w4 = *(const float4*)&wss[kk][tc * 4];
            float ya[4] = {y4.x, y4.y, y4.z, y4.w};
            float wa[4] = {w4.x, w4.y, w4.z, w4.w};
#pragma unroll
            for (int i = 0; i < 4; ++i)
#pragma unroll
                for (int j = 0; j < 4; ++j)
                    acc[i][j] = fmaf(ya[i], wa[j], acc[i][j]);
        }
    }

    float bb[4];
#pragma unroll
    for (int j = 0; j < 4; ++j) bb[j] = b3[n0 + tc * 4 + j];
#pragma unroll
    for (int i = 0; i < 4; ++i) {
        size_t o = (size_t)(m0 + tr * 4 + i) * D_ + n0 + tc * 4;
        float4 r;
        r.x = acc[i][0] + bb[0]; r.y = acc[i][1] + bb[1];
        r.z = acc[i][2] + bb[2]; r.w = acc[i][3] + bb[3];
        *(float4*)(out_small + o) = r;
    }
}

// ---------------- gather group outputs back to rows -------------------------
__global__ __launch_bounds__(256) void gather_out(const int* __restrict__ ids,
                                                  const float* __restrict__ out_small,
                                                  float* __restrict__ out) {
    const int c = blockIdx.x * 256 + threadIdx.x;   // one float4 chunk
    const int per_row = D_ / 4;                     // 128
    const int b = c / (N_ * per_row);
    const int rem = c % (N_ * per_row);
    const int n = rem / per_row;
    const int q = rem % per_row;
    const int g = ids[n];
    float4 val = *(const float4*)(out_small + ((size_t)b * G_ + g) * D_ + q * 4);
    *(float4*)(out + (size_t)c * 4) = val;
}

// ---------------- launcher --------------------------------------------------
extern "C" void kernel_launch(void* const* d_in, const int* in_sizes, int n_in,
                              void* d_out, int out_size, void* d_ws, size_t ws_size,
                              hipStream_t stream) {
    (void)in_sizes; (void)n_in; (void)out_size; (void)ws_size;
    const float* x   = (const float*)d_in[0];
    const int*   ids = (const int*)d_in[1];
    const float* w1  = (const float*)d_in[2];
    const float* b1  = (const float*)d_in[3];
    const float* w2  = (const float*)d_in[4];
    const float* b2  = (const float*)d_in[5];
    const float* w3  = (const float*)d_in[6];
    const float* b3  = (const float*)d_in[7];
    float* out = (float*)d_out;

    float* ws_f = (float*)d_ws;
    unsigned short* wB = (unsigned short*)ws_f;          // 1 MB
    float* biasB     = ws_f + 262144;                    // 4 KB
    float* pt        = biasB + 1024;                     // 8 MB  [b][tl][s4][512][2]
    float* y         = pt + 2097152;                     // 1 MB
    float* out_small = y + 262144;                       // 1 MB
    int*   perm      = (int*)(out_small + 262144);       // 32 KB
    int*   base      = perm + N_;
    int*   counts    = base + G_;
    int*   fg        = counts + G_;

    hipLaunchKernelGGL(cast_w, dim3(512), dim3(256), 0, stream, w1, b1, w2, b2, wB, biasB);
    hipLaunchKernelGGL(build_lists3, dim3(1), dim3(256), 0, stream, ids, counts, base, fg, perm);
    hipLaunchKernelGGL(gemm_fused, dim3(4096), dim3(256), 0, stream,
                       x, wB, biasB, perm, base, fg, pt);
    hipLaunchKernelGGL(combineC, dim3(G_, B_), dim3(256), 0, stream, pt, base, counts, fg, y);
    hipLaunchKernelGGL(gemm3, dim3(8, 8), dim3(256), 0, stream, y, w3, b3, out_small);
    hipLaunchKernelGGL(gather_out, dim3(32768), dim3(256), 0, stream, ids, out_small, out);
}

// Round 6
// 206.342 us; speedup vs baseline: 7.2800x; 1.0287x over previous
//
#include <hip/hip_runtime.h>
#include <hip/hip_bf16.h>
#include <math.h>

#define B_ 8
#define N_ 8192
#define D_ 512
#define G_ 64
#define M_ (B_ * N_)   // 65536

typedef short bf16x8 __attribute__((ext_vector_type(8)));
typedef float f32x4 __attribute__((ext_vector_type(4)));

__device__ __forceinline__ unsigned short f2bf(float f) {
    __hip_bfloat16 h = __float2bfloat16(f);
    return *reinterpret_cast<unsigned short*>(&h);
}
__device__ __forceinline__ void gload_lds16(const void* g, void* l) {
    __builtin_amdgcn_global_load_lds((const __attribute__((address_space(1))) void*)g,
                                     (__attribute__((address_space(3))) void*)l,
                                     16, 0, 0);
}

// ---------------- cast kernel (weights only; x is consumed f32 directly) ----
__global__ __launch_bounds__(256) void cast_w(const float* __restrict__ w1,
                                              const float* __restrict__ b1,
                                              const float* __restrict__ w2,
                                              const float* __restrict__ b2,
                                              unsigned short* __restrict__ wB,
                                              float* __restrict__ biasB) {
    int t = blockIdx.x * 256 + threadIdx.x;   // 0..131071, one float4
    int idx = t * 4;
    int row = idx >> 9;
    int col = idx & 511;
    const float* src = (row < 512) ? (w1 + (size_t)row * 512 + col)
                                   : (w2 + (size_t)(row - 512) * 512 + col);
    float4 f = *(const float4*)src;
    ushort4 u;
    u.x = f2bf(f.x); u.y = f2bf(f.y); u.z = f2bf(f.z); u.w = f2bf(f.w);
    *(ushort4*)(wB + idx) = u;
    if (t < 1024) biasB[t] = (t < 512) ? b1[t] : b2[t - 512];
}

// ---------------- group-sorted permutation, bases, tile->first-group --------
__global__ __launch_bounds__(256) void build_lists3(const int* __restrict__ ids,
                                                    int* __restrict__ counts,
                                                    int* __restrict__ baseO,
                                                    int* __restrict__ fgO,
                                                    int* __restrict__ perm) {
    __shared__ int sid[N_];                    // 32 KB
    __shared__ unsigned short hist[256][G_];   // 32 KB
    __shared__ int sbase[G_ + 1];
    const int t = threadIdx.x;
    for (int i = t; i < N_; i += 256) sid[i] = ids[i];
#pragma unroll
    for (int g = 0; g < G_; ++g) hist[t][g] = 0;
    __syncthreads();
    const int nb = t * 32;
    for (int k = 0; k < 32; ++k) hist[t][sid[nb + k]]++;
    __syncthreads();
    if (t < G_) {   // column-wise prefix over thread strips for group t
        int run = 0;
        for (int i = 0; i < 256; ++i) {
            int v = hist[i][t];
            hist[i][t] = (unsigned short)run;
            run += v;
        }
        counts[t] = run;
    }
    __syncthreads();
    if (t == 0) {
        int acc = 0;
        for (int g = 0; g < G_; ++g) { sbase[g] = acc; acc += counts[g]; }
        sbase[G_] = acc;
    }
    __syncthreads();
    if (t < G_) baseO[t] = sbase[t];
    if (t < G_) {   // first group of each 128-row tile
        const int row = t * 128;
        int g = 0;
        while (g + 1 < G_ && sbase[g + 1] <= row) ++g;
        fgO[t] = g;
    }
    // emit permutation (deterministic: strip order, then in-strip order)
    for (int k = 0; k < 32; ++k) {
        const int n = nb + k;
        const int g = sid[n];
        const int pos = sbase[g] + hist[t][g];
        hist[t][g]++;
        perm[pos] = n;
    }
}

// ---------------- fused GEMM + segment softmax-aggregate --------------------
// Per block: 128 permuted rows (one b, one tile) x 64 e-cols.
// A is reg-staged from f32 x: loads issued at iteration top and PINNED there
// via sched_barrier(0) (compiler sank them in R5 -> exposed latency), consumed
// (cvt+swizzled ds_write) after the MFMA phase. B via global_load_lds.
__global__ __launch_bounds__(256) void gemm_fused(const float* __restrict__ x,
                                                  const unsigned short* __restrict__ wB,
                                                  const float* __restrict__ biasB,
                                                  const int* __restrict__ perm,
                                                  const int* __restrict__ base,
                                                  const int* __restrict__ fg,
                                                  float* __restrict__ pt) {
    __shared__ unsigned short lsA[2][128 * 64];    // 2 x 16 KB
    __shared__ unsigned short lsB[2][2][64 * 64];  // 2 x 2 x 8 KB   (W1, W2 panels)

    // block swizzle: 8 et-blocks sharing an A-tile are same-XCD, 8 apart
    const int o  = blockIdx.x;            // 0..4095
    const int mt = (o & 7) + ((o >> 6) << 3);   // 0..511 global m-tile
    const int et = (o >> 3) & 7;                // 0..7 e-tile (64 cols)
    const int b  = mt >> 6;
    const int tl = mt & 63;
    const int r0 = tl * 128;              // perm-slab row base

    const int tid = threadIdx.x;
    const int l = tid & 63;
    const int w = tid >> 6;
    const int wm = w >> 1, wn = w & 1;    // 2x2 wave grid: rows 64, cols 32
    const int lr = l >> 3;                // staging row-in-chunk
    const int lslot = l & 7;              // staging 16B slot
    const int fr = l & 15;                // fragment row/col
    const int scol = 8 * (lslot ^ lr);    // pre-swizzled source col (elems)

    // per-lane permuted A source rows (fixed across K)
    int nrow[4];
#pragma unroll
    for (int q = 0; q < 4; ++q) nrow[q] = perm[r0 + (w * 4 + q) * 8 + lr];

    f32x4 acc_a[4][2], acc_v[4][2];
#pragma unroll
    for (int i = 0; i < 4; ++i)
#pragma unroll
        for (int j = 0; j < 2; ++j) {
            acc_a[i][j] = (f32x4){0.f, 0.f, 0.f, 0.f};
            acc_v[i][j] = (f32x4){0.f, 0.f, 0.f, 0.f};
        }

    float4 areg[8];
    auto loadA = [&](int kt) {   // issue 8 global f32x4 loads for tile kt
#pragma unroll
        for (int q = 0; q < 4; ++q) {
            const float* src = x + (((size_t)(b << 13) + nrow[q]) << 9) + kt + scol;
            areg[q * 2]     = *(const float4*)src;
            areg[q * 2 + 1] = *(const float4*)(src + 4);
        }
    };
    auto writeA = [&](int buf) { // cvt + swizzled ds_write (same image as gload_lds)
#pragma unroll
        for (int q = 0; q < 4; ++q) {
            const int c = w * 4 + q;
            union { unsigned short us[8]; uint4 v4; } pk;
            const float* f = (const float*)&areg[q * 2];
#pragma unroll
            for (int e = 0; e < 8; ++e) pk.us[e] = f2bf(f[e]);
            *(uint4*)((char*)&lsA[buf][0] + c * 1024 + l * 16) = pk.v4;
        }
    };
    auto stageB = [&](int buf, int kt) {
#pragma unroll
        for (int q = 0; q < 4; ++q) {
            const int p = q >> 1;
            const int c2 = (w << 1) | (q & 1);
            const int wr = p * 512 + et * 64 + c2 * 8 + lr;
            gload_lds16(wB + ((size_t)wr << 9) + kt + scol, &lsB[buf][p][c2 * 512]);
        }
    };

    loadA(0);
    stageB(0, 0);
    __builtin_amdgcn_sched_barrier(0);   // pin load issue above the consumer
    writeA(0);
    __syncthreads();
    int cur = 0;
    for (int t = 0; t < 8; ++t) {
        if (t < 7) { loadA((t + 1) * 64); stageB(cur ^ 1, (t + 1) * 64); }
        __builtin_amdgcn_sched_barrier(0);   // loads must issue BEFORE MFMA phase
#pragma unroll
        for (int ks = 0; ks < 2; ++ks) {
            const int ib = 8 * ((ks * 4 + (l >> 4)) ^ (fr & 7));   // swizzled in-row elems
            bf16x8 af[4], bq[2][2];
#pragma unroll
            for (int i = 0; i < 4; ++i)
                af[i] = *(const bf16x8*)&lsA[cur][(wm * 64 + i * 16 + fr) * 64 + ib];
#pragma unroll
            for (int p = 0; p < 2; ++p)
#pragma unroll
                for (int j = 0; j < 2; ++j)
                    bq[p][j] = *(const bf16x8*)&lsB[cur][p][(wn * 32 + j * 16 + fr) * 64 + ib];
#pragma unroll
            for (int i = 0; i < 4; ++i)
#pragma unroll
                for (int j = 0; j < 2; ++j) {
                    acc_a[i][j] = __builtin_amdgcn_mfma_f32_16x16x32_bf16(af[i], bq[0][j], acc_a[i][j], 0, 0, 0);
                    acc_v[i][j] = __builtin_amdgcn_mfma_f32_16x16x32_bf16(af[i], bq[1][j], acc_v[i][j], 0, 0, 0);
                }
        }
        if (t < 7) writeA(cur ^ 1);   // vmcnt waits only the 8 A-loads; B stays in flight
        __syncthreads();
        cur ^= 1;
    }

    // ---- epilogue: exp + segment reduce ----
    const int fg0 = fg[tl];
    const int bnd0 = (fg0 + 1 < G_) ? base[fg0 + 1] : (1 << 30);
    const int bnd1 = (fg0 + 2 < G_) ? base[fg0 + 2] : (1 << 30);
    const int bnd2 = (fg0 + 3 < G_) ? base[fg0 + 3] : (1 << 30);
    float b1c[2], b2c[2];
#pragma unroll
    for (int j = 0; j < 2; ++j) {
        const int col = et * 64 + wn * 32 + j * 16 + fr;
        b1c[j] = biasB[col];
        b2c[j] = biasB[512 + col];
    }
    float dpart[4][2] = {}, ypart[4][2] = {};
    const int rbase = r0 + wm * 64 + ((l >> 4) << 2);
#pragma unroll
    for (int i = 0; i < 4; ++i)
#pragma unroll
        for (int rr = 0; rr < 4; ++rr) {
            const int row = rbase + i * 16 + rr;
            const int s = (row >= bnd0) + (row >= bnd1) + (row >= bnd2);
#pragma unroll
            for (int j = 0; j < 2; ++j) {
                const float e = __expf(acc_a[i][j][rr] + b1c[j]);
                const float ey = e * (acc_v[i][j][rr] + b2c[j]);
#pragma unroll
                for (int s2 = 0; s2 < 4; ++s2) {
                    dpart[s2][j] += (s == s2) ? e : 0.f;
                    ypart[s2][j] += (s == s2) ? ey : 0.f;
                }
            }
        }
    // butterfly over lane bits 4,5 -> sum over the wave's 64 rows
#pragma unroll
    for (int s2 = 0; s2 < 4; ++s2)
#pragma unroll
        for (int j = 0; j < 2; ++j) {
            dpart[s2][j] += __shfl_xor(dpart[s2][j], 16);
            dpart[s2][j] += __shfl_xor(dpart[s2][j], 32);
            ypart[s2][j] += __shfl_xor(ypart[s2][j], 16);
            ypart[s2][j] += __shfl_xor(ypart[s2][j], 32);
        }
    float* red = (float*)&lsA[0][0];    // [wm][s][col64][2] = 4 KB
    if ((l >> 4) == 0) {
#pragma unroll
        for (int s2 = 0; s2 < 4; ++s2)
#pragma unroll
            for (int j = 0; j < 2; ++j) {
                const int colL = wn * 32 + j * 16 + fr;
                red[((wm * 4 + s2) * 64 + colL) * 2 + 0] = dpart[s2][j];
                red[((wm * 4 + s2) * 64 + colL) * 2 + 1] = ypart[s2][j];
            }
    }
    __syncthreads();
#pragma unroll
    for (int k = 0; k < 2; ++k) {
        const int idx = tid * 2 + k;      // 0..511
        const int dy = idx & 1;
        const int colL = (idx >> 1) & 63;
        const int s2 = idx >> 7;
        const float vsum = red[((0 * 4 + s2) * 64 + colL) * 2 + dy] +
                           red[((1 * 4 + s2) * 64 + colL) * 2 + dy];
        pt[((((size_t)(b * 64 + tl)) * 4 + s2) * 512 + et * 64 + colL) * 2 + dy] = vsum;
    }
}

// ---------------- ordered cross-tile combine -> y[b][g][col] ----------------
__global__ __launch_bounds__(256) void combineC(const float* __restrict__ pt,
                                                const int* __restrict__ base,
                                                const int* __restrict__ counts,
                                                const int* __restrict__ fg,
                                                float* __restrict__ y) {
    const int g = blockIdx.x, b = blockIdx.y;
    const int bs = base[g];
    int cnt = counts[g];
    if (cnt == 0) cnt = 1;
    const int t0 = bs >> 7, t1 = (bs + cnt - 1) >> 7;
    for (int c = threadIdx.x; c < 512; c += 256) {
        float d = 0.f, yy = 0.f;
        for (int t = t0; t <= t1; ++t) {
            const int s = g - fg[t];
            if (s >= 0 && s < 4) {
                const float* p = &pt[((((size_t)(b * 64 + t)) * 4 + s) * 512 + c) * 2];
                d += p[0];
                yy += p[1];
            }
        }
        y[((size_t)(b * G_ + g)) * 512 + c] = yy / d;
    }
}

// ---------------- small GEMM: out_small = y @ w3^T + b3 (f32 vector) --------
__global__ __launch_bounds__(256) void gemm3(const float* __restrict__ y,
                                             const float* __restrict__ w3,
                                             const float* __restrict__ b3,
                                             float* __restrict__ out_small) {
    __shared__ float ys[16][68];
    __shared__ float wss[16][68];
    const int m0 = blockIdx.x * 64;
    const int n0 = blockIdx.y * 64;
    const int tid = threadIdx.x;
    const int tr = tid >> 4;
    const int tc = tid & 15;
    const int lrow = tid >> 2;
    const int lk4 = (tid & 3) * 4;

    float acc[4][4] = {};

    for (int k0 = 0; k0 < D_; k0 += 16) {
        float4 yv = *(const float4*)(y + (size_t)(m0 + lrow) * D_ + k0 + lk4);
        float4 wv = *(const float4*)(w3 + (size_t)(n0 + lrow) * D_ + k0 + lk4);
        __syncthreads();
        ys[lk4 + 0][lrow] = yv.x;  ys[lk4 + 1][lrow] = yv.y;
        ys[lk4 + 2][lrow] = yv.z;  ys[lk4 + 3][lrow] = yv.w;
        wss[lk4 + 0][lrow] = wv.x; wss[lk4 + 1][lrow] = wv.y;
        wss[lk4 + 2][lrow] = wv.z; wss[lk4 + 3][lrow] = wv.w;
        __syncthreads();
#pragma unroll
        for (int kk = 0; kk < 16; ++kk) {
            float4 y4 = *(const float4*)&ys[kk][tr * 4];
            float4 w4 = *(const float4*)&wss[kk][tc * 4];
            float ya[4] = {y4.x, y4.y, y4.z, y4.w};
            float wa[4] = {w4.x, w4.y, w4.z, w4.w};
#pragma unroll
            for (int i = 0; i < 4; ++i)
#pragma unroll
                for (int j = 0; j < 4; ++j)
                    acc[i][j] = fmaf(ya[i], wa[j], acc[i][j]);
        }
    }

    float bb[4];
#pragma unroll
    for (int j = 0; j < 4; ++j) bb[j] = b3[n0 + tc * 4 + j];
#pragma unroll
    for (int i = 0; i < 4; ++i) {
        size_t o = (size_t)(m0 + tr * 4 + i) * D_ + n0 + tc * 4;
        float4 r;
        r.x = acc[i][0] + bb[0]; r.y = acc[i][1] + bb[1];
        r.z = acc[i][2] + bb[2]; r.w = acc[i][3] + bb[3];
        *(float4*)(out_small + o) = r;
    }
}

// ---------------- gather group outputs back to rows -------------------------
__global__ __launch_bounds__(256) void gather_out(const int* __restrict__ ids,
                                                  const float* __restrict__ out_small,
                                                  float* __restrict__ out) {
    const int c = blockIdx.x * 256 + threadIdx.x;   // one float4 chunk
    const int per_row = D_ / 4;                     // 128
    const int b = c / (N_ * per_row);
    const int rem = c % (N_ * per_row);
    const int n = rem / per_row;
    const int q = rem % per_row;
    const int g = ids[n];
    float4 val = *(const float4*)(out_small + ((size_t)b * G_ + g) * D_ + q * 4);
    *(float4*)(out + (size_t)c * 4) = val;
}

// ---------------- launcher --------------------------------------------------
extern "C" void kernel_launch(void* const* d_in, const int* in_sizes, int n_in,
                              void* d_out, int out_size, void* d_ws, size_t ws_size,
                              hipStream_t stream) {
    (void)in_sizes; (void)n_in; (void)out_size; (void)ws_size;
    const float* x   = (const float*)d_in[0];
    const int*   ids = (const int*)d_in[1];
    const float* w1  = (const float*)d_in[2];
    const float* b1  = (const float*)d_in[3];
    const float* w2  = (const float*)d_in[4];
    const float* b2  = (const float*)d_in[5];
    const float* w3  = (const float*)d_in[6];
    const float* b3  = (const float*)d_in[7];
    float* out = (float*)d_out;

    float* ws_f = (float*)d_ws;
    unsigned short* wB = (unsigned short*)ws_f;          // 1 MB
    float* biasB     = ws_f + 262144;                    // 4 KB
    float* pt        = biasB + 1024;                     // 8 MB  [b][tl][s4][512][2]
    float* y         = pt + 2097152;                     // 1 MB
    float* out_small = y + 262144;                       // 1 MB
    int*   perm      = (int*)(out_small + 262144);       // 32 KB
    int*   base      = perm + N_;
    int*   counts    = base + G_;
    int*   fg        = counts + G_;

    hipLaunchKernelGGL(cast_w, dim3(512), dim3(256), 0, stream, w1, b1, w2, b2, wB, biasB);
    hipLaunchKernelGGL(build_lists3, dim3(1), dim3(256), 0, stream, ids, counts, base, fg, perm);
    hipLaunchKernelGGL(gemm_fused, dim3(4096), dim3(256), 0, stream,
                       x, wB, biasB, perm, base, fg, pt);
    hipLaunchKernelGGL(combineC, dim3(G_, B_), dim3(256), 0, stream, pt, base, counts, fg, y);
    hipLaunchKernelGGL(gemm3, dim3(8, 8), dim3(256), 0, stream, y, w3, b3, out_small);
    hipLaunchKernelGGL(gather_out, dim3(32768), dim3(256), 0, stream, ids, out_small, out);
}